// Round 5
// baseline (574.669 us; speedup 1.0000x reference)
//
#include <hip/hip_runtime.h>

// ---------------------------------------------------------------------------
// ComplexHoloLinear: out[n,r] = sum_k x[n,k] * (Wr[r,k] + cos(phase[b])*Wi[r,k])
// b = n / SEQ.  Wr/Wi dense-assembled from COO (duplicates sum).
//
// Pipeline: memset -> {scatter || xconv fused} -> fold -> bf16 MFMA GEMM
// (256x256 tile, counted-vmcnt dbuf, 4-phase quadrant schedule, XOR-swizzle).
// ---------------------------------------------------------------------------

#define K_IN   4096
#define F_OUT  4096
#define SEQ    2048
#define NROW   8192            // BATCH * SEQ
#define NNZ    4194304
#define WELEM  16777216        // F_OUT * K_IN

typedef float  f32x4  __attribute__((ext_vector_type(4)));
typedef __bf16 bf16x8 __attribute__((ext_vector_type(8)));
typedef unsigned short u16x8 __attribute__((ext_vector_type(8)));

__device__ __forceinline__ unsigned short f2bf(float f) {
  unsigned u = __builtin_bit_cast(unsigned, f);
  u += 0x7fffu + ((u >> 16) & 1u);          // round-to-nearest-even
  return (unsigned short)(u >> 16);
}
__device__ __forceinline__ float bf2f(unsigned short b) {
  return __builtin_bit_cast(float, (unsigned)b << 16);
}

// ---------------- 1. fused: scatter COO (pk_add_bf16)  ||  x f32->bf16 ----
__global__ __launch_bounds__(256) void scatxconv_kernel(
    const int* __restrict__ rows, const int* __restrict__ cols,
    const float* __restrict__ wre, const float* __restrict__ wim,
    unsigned short* __restrict__ Wcb,
    const float* __restrict__ x, unsigned short* __restrict__ Xb) {
  int b = blockIdx.x;
  if (b < NNZ / 256) {                       // scatter half
    int e = b * 256 + threadIdx.x;
    int r = rows[e];
    int c = cols[e];
    unsigned pk = (unsigned)f2bf(wre[e]) | ((unsigned)f2bf(wim[e]) << 16);
    size_t idx = ((size_t)r << 12) + (size_t)c;
    asm volatile("global_atomic_pk_add_bf16 %0, %1, off"
                 :: "v"(Wcb + (idx << 1)), "v"(pk) : "memory");
  } else {                                   // xconv half
    size_t i8 = ((size_t)(b - NNZ / 256) * 256 + threadIdx.x) << 3;
    f32x4 a = *(const f32x4*)(x + i8);
    f32x4 c = *(const f32x4*)(x + i8 + 4);
    u16x8 v;
    v[0] = f2bf(a[0]); v[1] = f2bf(a[1]); v[2] = f2bf(a[2]); v[3] = f2bf(a[3]);
    v[4] = f2bf(c[0]); v[5] = f2bf(c[1]); v[6] = f2bf(c[2]); v[7] = f2bf(c[3]);
    *(u16x8*)(Xb + i8) = v;
  }
}

// standalone versions (fallback path, small ws)
__global__ __launch_bounds__(256) void scatter_kernel(
    const int* __restrict__ rows, const int* __restrict__ cols,
    const float* __restrict__ wre, const float* __restrict__ wim,
    unsigned short* __restrict__ Wcb) {
  int e = blockIdx.x * 256 + threadIdx.x;
  int r = rows[e];
  int c = cols[e];
  unsigned pk = (unsigned)f2bf(wre[e]) | ((unsigned)f2bf(wim[e]) << 16);
  size_t idx = ((size_t)r << 12) + (size_t)c;
  asm volatile("global_atomic_pk_add_bf16 %0, %1, off"
               :: "v"(Wcb + (idx << 1)), "v"(pk) : "memory");
}
__global__ __launch_bounds__(256) void xconv_kernel(
    const float* __restrict__ x, unsigned short* __restrict__ Xb) {
  size_t i8 = ((size_t)blockIdx.x * 256 + threadIdx.x) << 3;
  f32x4 a = *(const f32x4*)(x + i8);
  f32x4 c = *(const f32x4*)(x + i8 + 4);
  u16x8 v;
  v[0] = f2bf(a[0]); v[1] = f2bf(a[1]); v[2] = f2bf(a[2]); v[3] = f2bf(a[3]);
  v[4] = f2bf(c[0]); v[5] = f2bf(c[1]); v[6] = f2bf(c[2]); v[7] = f2bf(c[3]);
  *(u16x8*)(Xb + i8) = v;
}

// ---------------- 2. fold phase: Wb[b] = bf16(Wr + cos_b * Wi) ------------
__global__ __launch_bounds__(256) void fold_kernel(
    const unsigned short* __restrict__ Wcb, const float* __restrict__ phase,
    unsigned short* __restrict__ Wb) {
  size_t i8 = ((size_t)blockIdx.x * 256 + threadIdx.x) << 3;  // 8 logical elems
  float cb[4];
  cb[0] = cosf(phase[0]); cb[1] = cosf(phase[1]);
  cb[2] = cosf(phase[2]); cb[3] = cosf(phase[3]);
  const unsigned short* p = Wcb + (i8 << 1);   // 16 shorts = 8 (r,i) pairs
  u16x8 a = *(const u16x8*)(p);
  u16x8 b = *(const u16x8*)(p + 8);
  float rr[8], ii[8];
  rr[0] = bf2f(a[0]); ii[0] = bf2f(a[1]);
  rr[1] = bf2f(a[2]); ii[1] = bf2f(a[3]);
  rr[2] = bf2f(a[4]); ii[2] = bf2f(a[5]);
  rr[3] = bf2f(a[6]); ii[3] = bf2f(a[7]);
  rr[4] = bf2f(b[0]); ii[4] = bf2f(b[1]);
  rr[5] = bf2f(b[2]); ii[5] = bf2f(b[3]);
  rr[6] = bf2f(b[4]); ii[6] = bf2f(b[5]);
  rr[7] = bf2f(b[6]); ii[7] = bf2f(b[7]);
  #pragma unroll
  for (int bb = 0; bb < 4; ++bb) {
    float c = cb[bb];
    u16x8 v;
    #pragma unroll
    for (int j = 0; j < 8; ++j) v[j] = f2bf(rr[j] + c * ii[j]);
    *(u16x8*)(Wb + ((size_t)bb << 24) + i8) = v;   // bb * 16777216 elems
  }
}

// ---------------- 3. bf16 GEMM: out = Xb @ Wb[batch]^T --------------------
// 256x256 tile, BK=64, 512 thr (8 waves 2x4), per-wave 128x64 output.
// Tile-level sync (proven R4): burst STAGE8 -> vmcnt(8) -> barrier ->
// compute -> trailing barrier.  NEW: compute split into 4 quadrant phases
// (12/4/8/0 ds_reads; barrier; setprio; 16 MFMA; setprio; barrier) so the
// block's LDS read-bursts are issued ahead and overlap the MFMA clusters.
#define GLOAD_LDS(g, l)                                                        \
  __builtin_amdgcn_global_load_lds(                                            \
      (const __attribute__((address_space(1))) unsigned int*)(g),              \
      (__attribute__((address_space(3))) unsigned int*)(l), 16, 0, 0)

__global__ __launch_bounds__(512, 2) void gemm_kernel(
    const unsigned short* __restrict__ Xb,   // [8192][4096] bf16 bits
    const unsigned short* __restrict__ Wb,   // [4][4096][4096] bf16 bits
    float* __restrict__ out) {               // [8192][4096] f32
  __shared__ unsigned short lds[65536];      // 128KB: [buf][A|B][256][64]

  const int tid  = threadIdx.x;
  const int wid  = tid >> 6;                 // 0..7
  const int lane = tid & 63;
  const int wr   = wid >> 2;                 // wave row 0..1 (128 rows each)
  const int wc   = wid & 3;                  // wave col 0..3 (64 cols each)

  const int bid  = blockIdx.x;               // 0..511
  const int swz  = ((bid & 7) << 6) | (bid >> 3);  // xcd*64 + idx (512%8==0)
  const int brow = swz >> 4;                 // 0..31
  const int bcol = swz & 15;                 // 0..15
  const size_t M0 = (size_t)brow << 8;       // *256
  const int batch = brow >> 3;               // 2048 rows/batch / 256
  const unsigned short* Ap = Xb + M0 * K_IN;
  const unsigned short* Bp = Wb + ((size_t)batch << 24) + (((size_t)bcol << 8) * K_IN);

  // staging geometry
  const int srow = lane >> 3;                // 0..7 == row&7
  const int gsl  = ((lane & 7) ^ srow) << 3; // pre-swizzled k-elem offset
  // fragment geometry
  const int lrow = lane & 15;
  const int lr7  = lane & 7;
  const int sb   = lane >> 4;                // 0..3

  f32x4 acc[8][4] = {};
  bf16x8 af[8], bf0[4], bf1[4];              // A m-quad (both k-steps), B n-pairs

#define STAGE(buf, k0)                                                         \
  {                                                                            \
    _Pragma("unroll")                                                          \
    for (int l = 0; l < 4; ++l) {                                              \
      const int rr = (l << 6) + (wid << 3);                                    \
      GLOAD_LDS(Ap + (size_t)(rr + srow) * K_IN + (size_t)((k0) + gsl),        \
                &lds[((buf) << 15) + (rr << 6)]);                              \
    }                                                                          \
    _Pragma("unroll")                                                          \
    for (int l = 0; l < 4; ++l) {                                              \
      const int rr = (l << 6) + (wid << 3);                                    \
      GLOAD_LDS(Bp + (size_t)(rr + srow) * K_IN + (size_t)((k0) + gsl),        \
                &lds[((buf) << 15) + 16384 + (rr << 6)]);                      \
    }                                                                          \
  }

#define BAR asm volatile("s_barrier" ::: "memory")

  // 4-phase quadrant compute of buf. cs0/cs1 = swizzled k-columns t0/t1.
#define PHASES(buf)                                                            \
  {                                                                            \
    const unsigned short* la = &lds[(buf) << 15];                              \
    const unsigned short* lb = &lds[((buf) << 15) + 16384];                    \
    const int cs0 = (sb ^ lr7) << 3;                                           \
    const int cs1 = ((4 + sb) ^ lr7) << 3;                                     \
    /* q0: A m0-3 (12 reads: 8A+4B), B n0-1 */                                 \
    _Pragma("unroll")                                                          \
    for (int m = 0; m < 4; ++m) {                                              \
      const int ro = ((wr << 7) + (m << 4) + lrow) << 6;                       \
      af[m]     = *(const bf16x8*)&la[ro + cs0];                               \
      af[m + 4] = *(const bf16x8*)&la[ro + cs1];                               \
    }                                                                          \
    _Pragma("unroll")                                                          \
    for (int n = 0; n < 2; ++n) {                                              \
      const int ro = ((wc << 6) + (n << 4) + lrow) << 6;                       \
      bf0[n]     = *(const bf16x8*)&lb[ro + cs0];                              \
      bf0[n + 2] = *(const bf16x8*)&lb[ro + cs1];                              \
    }                                                                          \
    BAR;                                                                       \
    __builtin_amdgcn_s_setprio(1);                                             \
    _Pragma("unroll")                                                          \
    for (int m = 0; m < 4; ++m)                                                \
      _Pragma("unroll")                                                        \
      for (int n = 0; n < 2; ++n) {                                            \
        acc[m][n] = __builtin_amdgcn_mfma_f32_16x16x32_bf16(af[m], bf0[n], acc[m][n], 0, 0, 0); \
        acc[m][n] = __builtin_amdgcn_mfma_f32_16x16x32_bf16(af[m + 4], bf0[n + 2], acc[m][n], 0, 0, 0); \
      }                                                                        \
    __builtin_amdgcn_s_setprio(0);                                             \
    BAR;                                                                       \
    /* q1: B n2-3 (4 reads), reuse A m0-3 */                                   \
    _Pragma("unroll")                                                          \
    for (int n = 0; n < 2; ++n) {                                              \
      const int ro = ((wc << 6) + ((n + 2) << 4) + lrow) << 6;                 \
      bf1[n]     = *(const bf16x8*)&lb[ro + cs0];                              \
      bf1[n + 2] = *(const bf16x8*)&lb[ro + cs1];                              \
    }                                                                          \
    BAR;                                                                       \
    __builtin_amdgcn_s_setprio(1);                                             \
    _Pragma("unroll")                                                          \
    for (int m = 0; m < 4; ++m)                                                \
      _Pragma("unroll")                                                        \
      for (int n = 0; n < 2; ++n) {                                            \
        acc[m][n + 2] = __builtin_amdgcn_mfma_f32_16x16x32_bf16(af[m], bf1[n], acc[m][n + 2], 0, 0, 0); \
        acc[m][n + 2] = __builtin_amdgcn_mfma_f32_16x16x32_bf16(af[m + 4], bf1[n + 2], acc[m][n + 2], 0, 0, 0); \
      }                                                                        \
    __builtin_amdgcn_s_setprio(0);                                             \
    BAR;                                                                       \
    /* q2: A m4-7 (8 reads), reuse B n0-1 */                                   \
    _Pragma("unroll")                                                          \
    for (int m = 0; m < 4; ++m) {                                              \
      const int ro = ((wr << 7) + ((m + 4) << 4) + lrow) << 6;                 \
      af[m]     = *(const bf16x8*)&la[ro + cs0];                               \
      af[m + 4] = *(const bf16x8*)&la[ro + cs1];                               \
    }                                                                          \
    BAR;                                                                       \
    __builtin_amdgcn_s_setprio(1);                                             \
    _Pragma("unroll")                                                          \
    for (int m = 0; m < 4; ++m)                                                \
      _Pragma("unroll")                                                        \
      for (int n = 0; n < 2; ++n) {                                            \
        acc[m + 4][n] = __builtin_amdgcn_mfma_f32_16x16x32_bf16(af[m], bf0[n], acc[m + 4][n], 0, 0, 0); \
        acc[m + 4][n] = __builtin_amdgcn_mfma_f32_16x16x32_bf16(af[m + 4], bf0[n + 2], acc[m + 4][n], 0, 0, 0); \
      }                                                                        \
    __builtin_amdgcn_s_setprio(0);                                             \
    BAR;                                                                       \
    /* q3: no reads, reuse A m4-7 x B n2-3 */                                  \
    __builtin_amdgcn_s_setprio(1);                                             \
    _Pragma("unroll")                                                          \
    for (int m = 0; m < 4; ++m)                                                \
      _Pragma("unroll")                                                        \
      for (int n = 0; n < 2; ++n) {                                            \
        acc[m + 4][n + 2] = __builtin_amdgcn_mfma_f32_16x16x32_bf16(af[m], bf1[n], acc[m + 4][n + 2], 0, 0, 0); \
        acc[m + 4][n + 2] = __builtin_amdgcn_mfma_f32_16x16x32_bf16(af[m + 4], bf1[n + 2], acc[m + 4][n + 2], 0, 0, 0); \
      }                                                                        \
    __builtin_amdgcn_s_setprio(0);                                             \
    BAR;  /* trailing: all reads of buf done -> next STAGE may overwrite */    \
  }

  STAGE(0, 0);                               // prologue: tile 0 -> buf0
  int cur = 0;
  for (int t = 0; t < 63; ++t) {
    STAGE(cur ^ 1, (t + 1) << 6);            // issue next tile, keep in flight
    asm volatile("s_waitcnt vmcnt(8)\n\ts_barrier" ::: "memory"); // tile t landed
    PHASES(cur);
    cur ^= 1;
  }
  asm volatile("s_waitcnt vmcnt(0)\n\ts_barrier" ::: "memory");
  PHASES(cur);

  // epilogue: C/D layout col = lane&15, row = (lane>>4)*4 + j  [m89/m91]
  const int ch = lane >> 4;
  float* op = out + (M0 + (size_t)(wr << 7)) * F_OUT + ((size_t)bcol << 8) + (wc << 6);
  #pragma unroll
  for (int m = 0; m < 8; ++m)
    #pragma unroll
    for (int n = 0; n < 4; ++n)
      #pragma unroll
      for (int j = 0; j < 4; ++j)
        op[(size_t)((m << 4) + (ch << 2) + j) * F_OUT + (n << 4) + lrow] = acc[m][n][j];
#undef STAGE
#undef PHASES
#undef BAR
}

// ---------------- fallback (small ws): naive, reads bf16 pairs -------------
__global__ __launch_bounds__(256) void naive_kernel(
    const float* __restrict__ x, const unsigned short* __restrict__ Wcb,
    const float* __restrict__ phase, float* __restrict__ out) {
  int n = blockIdx.x >> 4;
  int r = ((blockIdx.x & 15) << 8) | threadIdx.x;
  float cb = cosf(phase[n >> 11]);
  const float* xp = x + ((size_t)n << 12);
  const unsigned short* wc = Wcb + (((size_t)r << 12) << 1);
  float ar = 0.f, ai = 0.f;
  for (int k = 0; k < K_IN; ++k) {
    float xv = xp[k];
    ar += xv * bf2f(wc[2 * k]);
    ai += xv * bf2f(wc[2 * k + 1]);
  }
  out[((size_t)n << 12) + r] = ar + cb * ai;
}

// ---------------------------------------------------------------------------
extern "C" void kernel_launch(void* const* d_in, const int* in_sizes, int n_in,
                              void* d_out, int out_size, void* d_ws, size_t ws_size,
                              hipStream_t stream) {
  const float* x     = (const float*)d_in[0];
  const int*   rows  = (const int*)d_in[1];
  const int*   cols  = (const int*)d_in[2];
  const float* wre   = (const float*)d_in[3];
  const float* wim   = (const float*)d_in[4];
  const float* phase = (const float*)d_in[5];
  float* out = (float*)d_out;

  unsigned short* Wcb = (unsigned short*)d_ws;   // [0, 64MB) bf16 (r,i) pairs

  hipMemsetAsync(d_ws, 0, (size_t)WELEM * 4, stream);   // 64MB

  const size_t WS_FULL = (size_t)268435456;  // 256MB: Wcb | Wb | Xb
  const size_t WS_MAIN = (size_t)201326592;  // 192MB: Wcb/Xb shared | Wb
  if (ws_size >= WS_FULL) {
    unsigned short* Wb = (unsigned short*)((char*)d_ws + (size_t)67108864);   // [64,192MB)
    unsigned short* Xb = (unsigned short*)((char*)d_ws + (size_t)201326592);  // [192,256MB)
    scatxconv_kernel<<<NNZ / 256 + NROW * K_IN / 8 / 256, 256, 0, stream>>>(
        rows, cols, wre, wim, Wcb, x, Xb);
    fold_kernel<<<WELEM / 8 / 256, 256, 0, stream>>>(Wcb, phase, Wb);
    gemm_kernel<<<512, 512, 0, stream>>>(Xb, Wb, out);
  } else if (ws_size >= WS_MAIN) {
    unsigned short* Wb = (unsigned short*)((char*)d_ws + (size_t)67108864);   // [64,192MB)
    unsigned short* Xb = (unsigned short*)d_ws;  // reuse Wcb region after fold
    scatter_kernel<<<NNZ / 256, 256, 0, stream>>>(rows, cols, wre, wim, Wcb);
    fold_kernel<<<WELEM / 8 / 256, 256, 0, stream>>>(Wcb, phase, Wb);
    xconv_kernel<<<(size_t)NROW * K_IN / 8 / 256, 256, 0, stream>>>(x, Xb);
    gemm_kernel<<<512, 512, 0, stream>>>(Xb, Wb, out);
  } else {
    scatter_kernel<<<NNZ / 256, 256, 0, stream>>>(rows, cols, wre, wim, Wcb);
    naive_kernel<<<NROW * 16, 256, 0, stream>>>(x, Wcb, phase, out);
  }
}

// Round 6
// 540.859 us; speedup vs baseline: 1.0625x; 1.0625x over previous
//
#include <hip/hip_runtime.h>

// ---------------------------------------------------------------------------
// ComplexHoloLinear: out[n,r] = sum_k x[n,k] * (Wr[r,k] + cos(phase[b])*Wi[r,k])
// b = n / SEQ.  Wr/Wi dense-assembled from COO (duplicates sum).
//
// Pipeline: memset -> {scatter || xconv fused} -> fold -> bf16 MFMA GEMM
// (256x256 tile, BK=32 k-half phases, counted vmcnt(4), XOR-swizzled LDS).
// ---------------------------------------------------------------------------

#define K_IN   4096
#define F_OUT  4096
#define SEQ    2048
#define NROW   8192            // BATCH * SEQ
#define NNZ    4194304
#define WELEM  16777216        // F_OUT * K_IN

typedef float  f32x4  __attribute__((ext_vector_type(4)));
typedef __bf16 bf16x8 __attribute__((ext_vector_type(8)));
typedef unsigned short u16x8 __attribute__((ext_vector_type(8)));

__device__ __forceinline__ unsigned short f2bf(float f) {
  unsigned u = __builtin_bit_cast(unsigned, f);
  u += 0x7fffu + ((u >> 16) & 1u);          // round-to-nearest-even
  return (unsigned short)(u >> 16);
}
__device__ __forceinline__ float bf2f(unsigned short b) {
  return __builtin_bit_cast(float, (unsigned)b << 16);
}

// ---------------- 1. fused: scatter COO (pk_add_bf16)  ||  x f32->bf16 ----
__global__ __launch_bounds__(256) void scatxconv_kernel(
    const int* __restrict__ rows, const int* __restrict__ cols,
    const float* __restrict__ wre, const float* __restrict__ wim,
    unsigned short* __restrict__ Wcb,
    const float* __restrict__ x, unsigned short* __restrict__ Xb) {
  int b = blockIdx.x;
  if (b < NNZ / 256) {                       // scatter half
    int e = b * 256 + threadIdx.x;
    int r = rows[e];
    int c = cols[e];
    unsigned pk = (unsigned)f2bf(wre[e]) | ((unsigned)f2bf(wim[e]) << 16);
    size_t idx = ((size_t)r << 12) + (size_t)c;
    asm volatile("global_atomic_pk_add_bf16 %0, %1, off"
                 :: "v"(Wcb + (idx << 1)), "v"(pk) : "memory");
  } else {                                   // xconv half
    size_t i8 = ((size_t)(b - NNZ / 256) * 256 + threadIdx.x) << 3;
    f32x4 a = *(const f32x4*)(x + i8);
    f32x4 c = *(const f32x4*)(x + i8 + 4);
    u16x8 v;
    v[0] = f2bf(a[0]); v[1] = f2bf(a[1]); v[2] = f2bf(a[2]); v[3] = f2bf(a[3]);
    v[4] = f2bf(c[0]); v[5] = f2bf(c[1]); v[6] = f2bf(c[2]); v[7] = f2bf(c[3]);
    *(u16x8*)(Xb + i8) = v;
  }
}

// standalone versions (fallback path, small ws)
__global__ __launch_bounds__(256) void scatter_kernel(
    const int* __restrict__ rows, const int* __restrict__ cols,
    const float* __restrict__ wre, const float* __restrict__ wim,
    unsigned short* __restrict__ Wcb) {
  int e = blockIdx.x * 256 + threadIdx.x;
  int r = rows[e];
  int c = cols[e];
  unsigned pk = (unsigned)f2bf(wre[e]) | ((unsigned)f2bf(wim[e]) << 16);
  size_t idx = ((size_t)r << 12) + (size_t)c;
  asm volatile("global_atomic_pk_add_bf16 %0, %1, off"
               :: "v"(Wcb + (idx << 1)), "v"(pk) : "memory");
}
__global__ __launch_bounds__(256) void xconv_kernel(
    const float* __restrict__ x, unsigned short* __restrict__ Xb) {
  size_t i8 = ((size_t)blockIdx.x * 256 + threadIdx.x) << 3;
  f32x4 a = *(const f32x4*)(x + i8);
  f32x4 c = *(const f32x4*)(x + i8 + 4);
  u16x8 v;
  v[0] = f2bf(a[0]); v[1] = f2bf(a[1]); v[2] = f2bf(a[2]); v[3] = f2bf(a[3]);
  v[4] = f2bf(c[0]); v[5] = f2bf(c[1]); v[6] = f2bf(c[2]); v[7] = f2bf(c[3]);
  *(u16x8*)(Xb + i8) = v;
}

// ---------------- 2. fold phase: Wb[b] = bf16(Wr + cos_b * Wi) ------------
__global__ __launch_bounds__(256) void fold_kernel(
    const unsigned short* __restrict__ Wcb, const float* __restrict__ phase,
    unsigned short* __restrict__ Wb) {
  size_t i8 = ((size_t)blockIdx.x * 256 + threadIdx.x) << 3;  // 8 logical elems
  float cb[4];
  cb[0] = cosf(phase[0]); cb[1] = cosf(phase[1]);
  cb[2] = cosf(phase[2]); cb[3] = cosf(phase[3]);
  const unsigned short* p = Wcb + (i8 << 1);   // 16 shorts = 8 (r,i) pairs
  u16x8 a = *(const u16x8*)(p);
  u16x8 b = *(const u16x8*)(p + 8);
  float rr[8], ii[8];
  rr[0] = bf2f(a[0]); ii[0] = bf2f(a[1]);
  rr[1] = bf2f(a[2]); ii[1] = bf2f(a[3]);
  rr[2] = bf2f(a[4]); ii[2] = bf2f(a[5]);
  rr[3] = bf2f(a[6]); ii[3] = bf2f(a[7]);
  rr[4] = bf2f(b[0]); ii[4] = bf2f(b[1]);
  rr[5] = bf2f(b[2]); ii[5] = bf2f(b[3]);
  rr[6] = bf2f(b[4]); ii[6] = bf2f(b[5]);
  rr[7] = bf2f(b[6]); ii[7] = bf2f(b[7]);
  #pragma unroll
  for (int bb = 0; bb < 4; ++bb) {
    float c = cb[bb];
    u16x8 v;
    #pragma unroll
    for (int j = 0; j < 8; ++j) v[j] = f2bf(rr[j] + c * ii[j]);
    *(u16x8*)(Wb + ((size_t)bb << 24) + i8) = v;   // bb * 16777216 elems
  }
}

// ---------------- 3. bf16 GEMM: out = Xb @ Wb[batch]^T --------------------
// 256x256 tile, 512 thr (8 waves 2x4), per-wave 128x64 output.
// K-tile = 64, split into 2 k-half PHASES (BK=32 = one MFMA K-step):
//   vmcnt(4) -> barrier -> 12 ds_read_b128 -> 4 gloads (next tile, same
//   khalf) -> lgkmcnt(0)+sched_barrier -> setprio(1) 32 MFMA setprio(0)
//   -> barrier.
// Staging spread 4/phase, loads in flight ~2 phases; vmcnt never drains.
// LDS [buf][khalf][A|B][256 rows][32 k], slot-swizzle s ^= (row>>1)&3
// (4 x 16B slots/row -> 2-way bank aliasing = free [m136]); global source
// pre-swizzled so gload_lds dest stays linear (rule #21).
#define GLOAD_LDS(g, l)                                                        \
  __builtin_amdgcn_global_load_lds(                                            \
      (const __attribute__((address_space(1))) unsigned int*)(g),              \
      (__attribute__((address_space(3))) unsigned int*)(l), 16, 0, 0)

__global__ __launch_bounds__(512, 2) void gemm_kernel(
    const unsigned short* __restrict__ Xb,   // [8192][4096] bf16 bits
    const unsigned short* __restrict__ Wb,   // [4][4096][4096] bf16 bits
    float* __restrict__ out) {               // [8192][4096] f32
  __shared__ unsigned short lds[65536];      // 128KB

  const int tid  = threadIdx.x;
  const int wid  = tid >> 6;                 // 0..7
  const int lane = tid & 63;
  const int wr   = wid >> 2;                 // wave row 0..1 (128 rows each)
  const int wc   = wid & 3;                  // wave col 0..3 (64 cols each)

  const int bid  = blockIdx.x;               // 0..511
  const int swz  = ((bid & 7) << 6) | (bid >> 3);  // xcd*64 + idx (512%8==0)
  const int brow = swz >> 4;                 // 0..31
  const int bcol = swz & 15;                 // 0..15
  const size_t M0 = (size_t)brow << 8;       // *256
  const int batch = brow >> 3;               // 2048 rows/batch / 256
  const unsigned short* Ap = Xb + M0 * K_IN;
  const unsigned short* Bp = Wb + ((size_t)batch << 24) + (((size_t)bcol << 8) * K_IN);

  // staging geometry: wave-load covers 16 rows x 32k; lane -> (row, slot)
  const int srow4 = lane >> 2;                        // row within 16-row chunk
  const int gslot = (((lane & 3) ^ ((lane >> 3) & 3)) << 3); // pre-swizzled k-elem off
  // fragment geometry
  const int lrow = lane & 15;
  const int sb   = lane >> 4;                         // k-slot 0..3
  const int fsl  = ((sb ^ ((lrow >> 1) & 3)) << 3);   // swizzled frag k-offset

  f32x4 acc[8][4] = {};

  // stage one k-half (h) of tile at kbase into buf: 2 A rounds + 2 B rounds
#define STAGEH(buf, h, kbase)                                                  \
  {                                                                            \
    _Pragma("unroll")                                                          \
    for (int l = 0; l < 2; ++l) {                                              \
      const int ch = ((l << 3) + wid) << 4;          /* 16-row chunk base */   \
      GLOAD_LDS(Ap + (size_t)(ch + srow4) * K_IN + (size_t)((kbase) + ((h) << 5) + gslot), \
                &lds[((buf) << 15) + ((h) << 14) + (ch << 5)]);                \
    }                                                                          \
    _Pragma("unroll")                                                          \
    for (int l = 0; l < 2; ++l) {                                              \
      const int ch = ((l << 3) + wid) << 4;                                    \
      GLOAD_LDS(Bp + (size_t)(ch + srow4) * K_IN + (size_t)((kbase) + ((h) << 5) + gslot), \
                &lds[((buf) << 15) + ((h) << 14) + 8192 + (ch << 5)]);         \
    }                                                                          \
  }

#define PHASE(N, cur, h, STG)                                                  \
  {                                                                            \
    asm volatile("s_waitcnt vmcnt(" #N ")" ::: "memory");                      \
    __builtin_amdgcn_s_barrier();                                              \
    const unsigned short* la = &lds[((cur) << 15) + ((h) << 14)];              \
    const unsigned short* lb = la + 8192;                                      \
    bf16x8 af[8], bff[4];                                                      \
    _Pragma("unroll")                                                          \
    for (int m = 0; m < 8; ++m)                                                \
      af[m] = *(const bf16x8*)&la[(((wr << 7) + (m << 4) + lrow) << 5) + fsl]; \
    _Pragma("unroll")                                                          \
    for (int n = 0; n < 4; ++n)                                                \
      bff[n] = *(const bf16x8*)&lb[(((wc << 6) + (n << 4) + lrow) << 5) + fsl];\
    STG;                                                                       \
    asm volatile("s_waitcnt lgkmcnt(0)" ::: "memory");                         \
    __builtin_amdgcn_sched_barrier(0);                                         \
    __builtin_amdgcn_s_setprio(1);                                             \
    _Pragma("unroll")                                                          \
    for (int m = 0; m < 8; ++m)                                                \
      _Pragma("unroll")                                                        \
      for (int n = 0; n < 4; ++n)                                              \
        acc[m][n] = __builtin_amdgcn_mfma_f32_16x16x32_bf16(                   \
            af[m], bff[n], acc[m][n], 0, 0, 0);                                \
    __builtin_amdgcn_s_setprio(0);                                             \
    __builtin_amdgcn_s_barrier();                                              \
  }

  STAGEH(0, 0, 0);                           // prologue: tile 0, both khalves
  STAGEH(0, 1, 0);
  for (int t = 0; t < 63; ++t) {
    const int cur = t & 1;
    PHASE(4, cur, 0, STAGEH(cur ^ 1, 0, (t + 1) << 6));
    PHASE(4, cur, 1, STAGEH(cur ^ 1, 1, (t + 1) << 6));
  }
  PHASE(4, 1, 0, );                          // tile 63 in buf1, no staging
  PHASE(0, 1, 1, );

  // epilogue: C/D layout col = lane&15, row = (lane>>4)*4 + j  [m89/m91]
  const int chh = lane >> 4;
  float* op = out + (M0 + (size_t)(wr << 7)) * F_OUT + ((size_t)bcol << 8) + (wc << 6);
  #pragma unroll
  for (int m = 0; m < 8; ++m)
    #pragma unroll
    for (int n = 0; n < 4; ++n)
      #pragma unroll
      for (int j = 0; j < 4; ++j)
        op[(size_t)((m << 4) + (chh << 2) + j) * F_OUT + (n << 4) + lrow] = acc[m][n][j];
#undef STAGEH
#undef PHASE
}

// ---------------- fallback (small ws): naive, reads bf16 pairs -------------
__global__ __launch_bounds__(256) void naive_kernel(
    const float* __restrict__ x, const unsigned short* __restrict__ Wcb,
    const float* __restrict__ phase, float* __restrict__ out) {
  int n = blockIdx.x >> 4;
  int r = ((blockIdx.x & 15) << 8) | threadIdx.x;
  float cb = cosf(phase[n >> 11]);
  const float* xp = x + ((size_t)n << 12);
  const unsigned short* wc = Wcb + (((size_t)r << 12) << 1);
  float ar = 0.f, ai = 0.f;
  for (int k = 0; k < K_IN; ++k) {
    float xv = xp[k];
    ar += xv * bf2f(wc[2 * k]);
    ai += xv * bf2f(wc[2 * k + 1]);
  }
  out[((size_t)n << 12) + r] = ar + cb * ai;
}

// ---------------------------------------------------------------------------
extern "C" void kernel_launch(void* const* d_in, const int* in_sizes, int n_in,
                              void* d_out, int out_size, void* d_ws, size_t ws_size,
                              hipStream_t stream) {
  const float* x     = (const float*)d_in[0];
  const int*   rows  = (const int*)d_in[1];
  const int*   cols  = (const int*)d_in[2];
  const float* wre   = (const float*)d_in[3];
  const float* wim   = (const float*)d_in[4];
  const float* phase = (const float*)d_in[5];
  float* out = (float*)d_out;

  unsigned short* Wcb = (unsigned short*)d_ws;   // [0, 64MB) bf16 (r,i) pairs

  hipMemsetAsync(d_ws, 0, (size_t)WELEM * 4, stream);   // 64MB

  const size_t WS_FULL = (size_t)268435456;  // 256MB: Wcb | Wb | Xb
  const size_t WS_MAIN = (size_t)201326592;  // 192MB: Wcb/Xb shared | Wb
  if (ws_size >= WS_FULL) {
    unsigned short* Wb = (unsigned short*)((char*)d_ws + (size_t)67108864);   // [64,192MB)
    unsigned short* Xb = (unsigned short*)((char*)d_ws + (size_t)201326592);  // [192,256MB)
    scatxconv_kernel<<<NNZ / 256 + NROW * K_IN / 8 / 256, 256, 0, stream>>>(
        rows, cols, wre, wim, Wcb, x, Xb);
    fold_kernel<<<WELEM / 8 / 256, 256, 0, stream>>>(Wcb, phase, Wb);
    gemm_kernel<<<512, 512, 0, stream>>>(Xb, Wb, out);
  } else if (ws_size >= WS_MAIN) {
    unsigned short* Wb = (unsigned short*)((char*)d_ws + (size_t)67108864);   // [64,192MB)
    unsigned short* Xb = (unsigned short*)d_ws;  // reuse Wcb region after fold
    scatter_kernel<<<NNZ / 256, 256, 0, stream>>>(rows, cols, wre, wim, Wcb);
    fold_kernel<<<WELEM / 8 / 256, 256, 0, stream>>>(Wcb, phase, Wb);
    xconv_kernel<<<(size_t)NROW * K_IN / 8 / 256, 256, 0, stream>>>(x, Xb);
    gemm_kernel<<<512, 512, 0, stream>>>(Xb, Wb, out);
  } else {
    scatter_kernel<<<NNZ / 256, 256, 0, stream>>>(rows, cols, wre, wim, Wcb);
    naive_kernel<<<NROW * 16, 256, 0, stream>>>(x, Wcb, phase, out);
  }
}